// Round 1
// baseline (607.599 us; speedup 1.0000x reference)
//
#include <hip/hip_runtime.h>
#include <math.h>

#define BATCH 8
#define NHEAD 16
#define HDIM 128
#define DMODEL 2048
#define MAXBLK 64
#define BLKSZ 64
#define KVLEN 4096
#define NSPLIT 16
#define CHUNK (KVLEN / NSPLIT)   // 256
#define PSTRIDE (HDIM + 2)       // 130 floats per partial: m, l, acc[128]

// ---------------- QKV projection: qkv[m][b][col] = hs[b,:] . W_m[col,:] + b_m[col]
// grid 384 blocks x 256 thr. Wave handles 4 columns of one matrix for all 8 batches.
__global__ __launch_bounds__(256) void qkv_kernel(
    const float* __restrict__ hs,
    const float* __restrict__ Wq, const float* __restrict__ bq,
    const float* __restrict__ Wk, const float* __restrict__ bk,
    const float* __restrict__ Wv, const float* __restrict__ bv,
    float* __restrict__ qkv_out)
{
    __shared__ float hsl[BATCH * DMODEL];   // 64 KB
    {
        const float4* hs4 = (const float4*)hs;
        float4* hsl4 = (float4*)hsl;
        for (int idx = threadIdx.x; idx < BATCH * DMODEL / 4; idx += 256)
            hsl4[idx] = hs4[idx];
    }
    __syncthreads();

    int wave = threadIdx.x >> 6;
    int lane = threadIdx.x & 63;
    int gw = blockIdx.x * 4 + wave;          // 0..1535
    int gcol = gw * 4;                        // 0..6143
    int m = gcol >> 11;                       // matrix id 0..2
    int colBase = gcol & (DMODEL - 1);
    const float* W    = (m == 0) ? Wq : (m == 1) ? Wk : Wv;
    const float* bias = (m == 0) ? bq : (m == 1) ? bk : bv;

    float acc[4][BATCH];
    #pragma unroll
    for (int c = 0; c < 4; ++c)
        #pragma unroll
        for (int b = 0; b < BATCH; ++b) acc[c][b] = 0.f;

    #pragma unroll
    for (int it = 0; it < DMODEL / 256; ++it) {   // 8 iterations
        int k0 = it * 256 + lane * 4;
        float4 w[4];
        #pragma unroll
        for (int c = 0; c < 4; ++c)
            w[c] = *(const float4*)(W + (size_t)(colBase + c) * DMODEL + k0);
        #pragma unroll
        for (int b = 0; b < BATCH; ++b) {
            float4 hv = *(const float4*)(hsl + b * DMODEL + k0);
            #pragma unroll
            for (int c = 0; c < 4; ++c)
                acc[c][b] += hv.x * w[c].x + hv.y * w[c].y + hv.z * w[c].z + hv.w * w[c].w;
        }
    }

    #pragma unroll
    for (int c = 0; c < 4; ++c) {
        #pragma unroll
        for (int b = 0; b < BATCH; ++b) {
            float r = acc[c][b];
            r += __shfl_xor(r, 32); r += __shfl_xor(r, 16); r += __shfl_xor(r, 8);
            r += __shfl_xor(r, 4);  r += __shfl_xor(r, 2);  r += __shfl_xor(r, 1);
            if (lane == 0)
                qkv_out[m * (BATCH * DMODEL) + b * DMODEL + colBase + c] = r + bias[colBase + c];
        }
    }
}

// ---------------- RoPE in place on q and k sections. grid 128 x 64.
__global__ void rope_kernel(float* __restrict__ qkv, const int* __restrict__ hist)
{
    int bh = blockIdx.x;
    int b = bh >> 4, h = bh & 15;
    int i = threadIdx.x;            // 0..63
    int pos = hist[b];
    double f = (double)pos * pow(10000.0, -(double)i / 64.0);
    double sd, cd;
    sincos(f, &sd, &cd);
    float s = (float)sd, c = (float)cd;
    float* qp = qkv + b * DMODEL + h * HDIM;
    float* kp = qkv + BATCH * DMODEL + b * DMODEL + h * HDIM;
    float q1 = qp[i], q2 = qp[i + 64];
    qp[i]      = q1 * c - q2 * s;
    qp[i + 64] = q2 * c + q1 * s;
    float k1 = kp[i], k2 = kp[i + 64];
    kp[i]      = k1 * c - k2 * s;
    kp[i + 64] = k2 * c + k1 * s;
}

// ---------------- Flash-decode attention, split-KV. grid (NSPLIT, B*H) x 256.
__global__ __launch_bounds__(256) void attn_kernel(
    const float* __restrict__ qkv,
    const float* __restrict__ k_cache, const float* __restrict__ v_cache,
    const int* __restrict__ hist, const int* __restrict__ bofs,
    float* __restrict__ partials)
{
    int split = blockIdx.x;
    int bh = blockIdx.y;
    int b = bh >> 4, h = bh & 15;
    int lane = threadIdx.x & 63;
    int w = threadIdx.x >> 6;
    int pos = hist[b];
    int start = split * CHUNK;
    int end = min(start + CHUNK, pos + 1);

    __shared__ float sm[4], sl[4], sacc[4][HDIM];

    const float* qp   = qkv + b * DMODEL + h * HDIM;
    const float* knew = qkv + BATCH * DMODEL + b * DMODEL + h * HDIM;
    const float* vnew = qkv + 2 * BATCH * DMODEL + b * DMODEL + h * HDIM;
    float2 q2 = *(const float2*)(qp + lane * 2);

    float m_run = -1e30f, l_run = 0.f;
    float2 o_acc = make_float2(0.f, 0.f);

    int s = start + w;
    float2 k2 = make_float2(0.f, 0.f), v2 = make_float2(0.f, 0.f);
    if (s < end) {
        const float *kp, *vp;
        if (s == pos) { kp = knew; vp = vnew; }
        else {
            int blk = bofs[b * MAXBLK + (s >> 6)];
            int base = ((blk * BLKSZ + (s & 63)) * NHEAD + h) * HDIM;
            kp = k_cache + base; vp = v_cache + base;
        }
        k2 = *(const float2*)(kp + lane * 2);
        v2 = *(const float2*)(vp + lane * 2);
    }
    while (s < end) {
        int sn = s + 4;
        float2 k2n = make_float2(0.f, 0.f), v2n = make_float2(0.f, 0.f);
        if (sn < end) {
            const float *kp, *vp;
            if (sn == pos) { kp = knew; vp = vnew; }
            else {
                int blk = bofs[b * MAXBLK + (sn >> 6)];
                int base = ((blk * BLKSZ + (sn & 63)) * NHEAD + h) * HDIM;
                kp = k_cache + base; vp = v_cache + base;
            }
            k2n = *(const float2*)(kp + lane * 2);
            v2n = *(const float2*)(vp + lane * 2);
        }
        float d = q2.x * k2.x + q2.y * k2.y;
        d += __shfl_xor(d, 32); d += __shfl_xor(d, 16); d += __shfl_xor(d, 8);
        d += __shfl_xor(d, 4);  d += __shfl_xor(d, 2);  d += __shfl_xor(d, 1);
        float score = d * 0.08838834764831845f;   // 1/sqrt(128)
        float m_new = fmaxf(m_run, score);
        float corr = __expf(m_run - m_new);
        float p = __expf(score - m_new);
        l_run = l_run * corr + p;
        o_acc.x = o_acc.x * corr + p * v2.x;
        o_acc.y = o_acc.y * corr + p * v2.y;
        m_run = m_new;
        k2 = k2n; v2 = v2n; s = sn;
    }

    if (lane == 0) { sm[w] = m_run; sl[w] = l_run; }
    sacc[w][lane * 2]     = o_acc.x;
    sacc[w][lane * 2 + 1] = o_acc.y;
    __syncthreads();

    float M = fmaxf(fmaxf(sm[0], sm[1]), fmaxf(sm[2], sm[3]));
    float* part = partials + (size_t)(bh * NSPLIT + split) * PSTRIDE;
    if (threadIdx.x < HDIM) {
        float a = 0.f;
        #pragma unroll
        for (int ww = 0; ww < 4; ++ww)
            a += sacc[ww][threadIdx.x] * __expf(sm[ww] - M);
        part[2 + threadIdx.x] = a;
    }
    if (threadIdx.x == 0) {
        float L = 0.f;
        #pragma unroll
        for (int ww = 0; ww < 4; ++ww) L += sl[ww] * __expf(sm[ww] - M);
        part[0] = M; part[1] = L;
    }
}

// ---------------- Combine splits. grid 128 x 128.
__global__ void combine_kernel(const float* __restrict__ partials, float* __restrict__ o)
{
    int bh = blockIdx.x;
    int i = threadIdx.x;    // 0..127
    int b = bh >> 4, h = bh & 15;
    const float* base = partials + (size_t)bh * NSPLIT * PSTRIDE;
    float mv[NSPLIT];
    float M = -1e30f;
    #pragma unroll
    for (int sp = 0; sp < NSPLIT; ++sp) { mv[sp] = base[sp * PSTRIDE]; M = fmaxf(M, mv[sp]); }
    float L = 0.f, a = 0.f;
    #pragma unroll
    for (int sp = 0; sp < NSPLIT; ++sp) {
        float e = __expf(mv[sp] - M);
        L += base[sp * PSTRIDE + 1] * e;
        a += base[sp * PSTRIDE + 2 + i] * e;
    }
    o[b * DMODEL + h * HDIM + i] = a / L;
}

// ---------------- Output projection. grid 128 x 256. Wave = 4 columns.
__global__ __launch_bounds__(256) void oproj_kernel(
    const float* __restrict__ o,
    const float* __restrict__ Wo, const float* __restrict__ bo,
    float* __restrict__ out)
{
    __shared__ float ol[BATCH * DMODEL];   // 64 KB
    {
        const float4* o4 = (const float4*)o;
        float4* ol4 = (float4*)ol;
        for (int idx = threadIdx.x; idx < BATCH * DMODEL / 4; idx += 256)
            ol4[idx] = o4[idx];
    }
    __syncthreads();

    int wave = threadIdx.x >> 6;
    int lane = threadIdx.x & 63;
    int gw = blockIdx.x * 4 + wave;     // 0..511
    int colBase = gw * 4;               // 0..2044

    float acc[4][BATCH];
    #pragma unroll
    for (int c = 0; c < 4; ++c)
        #pragma unroll
        for (int b = 0; b < BATCH; ++b) acc[c][b] = 0.f;

    #pragma unroll
    for (int it = 0; it < DMODEL / 256; ++it) {
        int k0 = it * 256 + lane * 4;
        float4 w[4];
        #pragma unroll
        for (int c = 0; c < 4; ++c)
            w[c] = *(const float4*)(Wo + (size_t)(colBase + c) * DMODEL + k0);
        #pragma unroll
        for (int b = 0; b < BATCH; ++b) {
            float4 hv = *(const float4*)(ol + b * DMODEL + k0);
            #pragma unroll
            for (int c = 0; c < 4; ++c)
                acc[c][b] += hv.x * w[c].x + hv.y * w[c].y + hv.z * w[c].z + hv.w * w[c].w;
        }
    }

    #pragma unroll
    for (int c = 0; c < 4; ++c) {
        #pragma unroll
        for (int b = 0; b < BATCH; ++b) {
            float r = acc[c][b];
            r += __shfl_xor(r, 32); r += __shfl_xor(r, 16); r += __shfl_xor(r, 8);
            r += __shfl_xor(r, 4);  r += __shfl_xor(r, 2);  r += __shfl_xor(r, 1);
            if (lane == 0)
                out[b * DMODEL + colBase + c] = r + bo[colBase + c];
        }
    }
}

extern "C" void kernel_launch(void* const* d_in, const int* in_sizes, int n_in,
                              void* d_out, int out_size, void* d_ws, size_t ws_size,
                              hipStream_t stream) {
    const float* hs      = (const float*)d_in[0];
    const float* k_cache = (const float*)d_in[1];
    const float* v_cache = (const float*)d_in[2];
    const float* Wq      = (const float*)d_in[3];
    const float* bq      = (const float*)d_in[4];
    const float* Wk      = (const float*)d_in[5];
    const float* bk      = (const float*)d_in[6];
    const float* Wv      = (const float*)d_in[7];
    const float* bv      = (const float*)d_in[8];
    const float* Wo      = (const float*)d_in[9];
    const float* bo      = (const float*)d_in[10];
    const int*   hist    = (const int*)d_in[11];
    const int*   bofs    = (const int*)d_in[12];
    float* out = (float*)d_out;

    float* ws = (float*)d_ws;
    float* qkv      = ws;                                   // 3*8*2048 = 49152
    float* partials = ws + 49152;                           // 128*16*130 = 266240
    float* o        = ws + 49152 + 266240;                  // 16384

    qkv_kernel<<<384, 256, 0, stream>>>(hs, Wq, bq, Wk, bk, Wv, bv, qkv);
    rope_kernel<<<BATCH * NHEAD, 64, 0, stream>>>(qkv, hist);
    attn_kernel<<<dim3(NSPLIT, BATCH * NHEAD), 256, 0, stream>>>(qkv, k_cache, v_cache, hist, bofs, partials);
    combine_kernel<<<BATCH * NHEAD, HDIM, 0, stream>>>(partials, o);
    oproj_kernel<<<128, 256, 0, stream>>>(o, Wo, bo, out);
}

// Round 2
// 568.396 us; speedup vs baseline: 1.0690x; 1.0690x over previous
//
#include <hip/hip_runtime.h>
#include <math.h>

#define BATCH 8
#define NHEAD 16
#define HDIM 128
#define DMODEL 2048
#define MAXBLK 64
#define BLKSZ 64
#define KVLEN 4096
#define NSPLIT 16
#define CHUNK (KVLEN / NSPLIT)   // 256
#define PSTRIDE 132              // float: [l, pad, pad, pad, acc[128]]
#define SCALE 0.08838834764831845f  // 1/sqrt(128)
// log2(10000)/64
#define L2T_64 0.20762050593046015f

// ---------------- QKV projection: qkv[m][b][col] = hs[b,:] . W_m[col,:] + b_m[col]
// grid 512 x 256. Wave handles 3 columns (of the 6144 q|k|v columns) for all 8 batches.
__global__ __launch_bounds__(256) void qkv_kernel(
    const float* __restrict__ hs,
    const float* __restrict__ Wq, const float* __restrict__ bq,
    const float* __restrict__ Wk, const float* __restrict__ bk,
    const float* __restrict__ Wv, const float* __restrict__ bv,
    float* __restrict__ qkv_out)
{
    __shared__ float hsl[BATCH * DMODEL];   // 64 KB -> 2 blocks/CU
    {
        const float4* hs4 = (const float4*)hs;
        float4* hsl4 = (float4*)hsl;
        for (int idx = threadIdx.x; idx < BATCH * DMODEL / 4; idx += 256)
            hsl4[idx] = hs4[idx];
    }
    __syncthreads();

    int wave = threadIdx.x >> 6;
    int lane = threadIdx.x & 63;
    int gw = blockIdx.x * 4 + wave;          // 0..2047
    int col0 = gw * 3;                        // 0..6141

    const float* Wc[3];
    const float* biasc[3];
    int clc[3], mc[3];
    #pragma unroll
    for (int c = 0; c < 3; ++c) {
        int col = col0 + c;
        int m = col >> 11;
        mc[c] = m; clc[c] = col & (DMODEL - 1);
        Wc[c]    = (m == 0) ? Wq : (m == 1) ? Wk : Wv;
        biasc[c] = (m == 0) ? bq : (m == 1) ? bk : bv;
    }

    float acc[3][BATCH];
    #pragma unroll
    for (int c = 0; c < 3; ++c)
        #pragma unroll
        for (int b = 0; b < BATCH; ++b) acc[c][b] = 0.f;

    #pragma unroll
    for (int it = 0; it < DMODEL / 256; ++it) {   // 8 iterations
        int k0 = it * 256 + lane * 4;
        float4 w[3];
        #pragma unroll
        for (int c = 0; c < 3; ++c)
            w[c] = *(const float4*)(Wc[c] + (size_t)clc[c] * DMODEL + k0);
        #pragma unroll
        for (int b = 0; b < BATCH; ++b) {
            float4 hv = *(const float4*)(hsl + b * DMODEL + k0);
            #pragma unroll
            for (int c = 0; c < 3; ++c)
                acc[c][b] += hv.x * w[c].x + hv.y * w[c].y + hv.z * w[c].z + hv.w * w[c].w;
        }
    }

    #pragma unroll
    for (int c = 0; c < 3; ++c) {
        #pragma unroll
        for (int b = 0; b < BATCH; ++b) {
            float r = acc[c][b];
            r += __shfl_xor(r, 32); r += __shfl_xor(r, 16); r += __shfl_xor(r, 8);
            r += __shfl_xor(r, 4);  r += __shfl_xor(r, 2);  r += __shfl_xor(r, 1);
            if (lane == 0)
                qkv_out[mc[c] * (BATCH * DMODEL) + b * DMODEL + clc[c]] = r + biasc[c][clc[c]];
        }
    }
}

// ---------------- Flash-decode attention, split-KV, fused RoPE, no-max softmax.
// grid (NSPLIT, B*H) x 256. Half-wave (32 lanes x float4) per position, 2 pos/wave/iter.
__global__ __launch_bounds__(256) void attn_kernel(
    const float* __restrict__ qkv,
    const float* __restrict__ k_cache, const float* __restrict__ v_cache,
    const int* __restrict__ hist, const int* __restrict__ bofs,
    float* __restrict__ partials)
{
    int split = blockIdx.x;
    int bh = blockIdx.y;
    int b = bh >> 4, h = bh & 15;
    int tid = threadIdx.x;
    int w = tid >> 6;
    int lane = tid & 63;
    int half = lane >> 5;
    int l32 = lane & 31;
    int pos = hist[b];
    int start = split * CHUNK;
    int end = min(start + CHUNK, pos + 1);

    const float* qp   = qkv + b * DMODEL + h * HDIM;
    const float* knew = qkv + BATCH * DMODEL + b * DMODEL + h * HDIM;
    const float* vnew = qkv + 2 * BATCH * DMODEL + b * DMODEL + h * HDIM;

    // ---- load q / k_new fragments (4 dims per lane) and apply RoPE in-register
    int dbase = l32 * 4;              // 0..124
    int fi = dbase & 63;              // freq index base (same for all 4 dims, no wrap)
    float sgn = (dbase < 64) ? -1.f : 1.f;
    float4 q4  = *(const float4*)(qp + dbase);
    float4 qo  = *(const float4*)(qp + (dbase ^ 64));
    float4 kn4 = *(const float4*)(knew + dbase);
    float4 kno = *(const float4*)(knew + (dbase ^ 64));
    float4 vn4 = *(const float4*)(vnew + dbase);
    float fpos = (float)pos;
    float cs[4], sn[4];
    #pragma unroll
    for (int j = 0; j < 4; ++j) {
        float inv = exp2f(-(float)(fi + j) * L2T_64);
        float f = fpos * inv;
        sn[j] = sinf(f);
        cs[j] = cosf(f);
    }
    q4.x = q4.x * cs[0] + sgn * qo.x * sn[0];
    q4.y = q4.y * cs[1] + sgn * qo.y * sn[1];
    q4.z = q4.z * cs[2] + sgn * qo.z * sn[2];
    q4.w = q4.w * cs[3] + sgn * qo.w * sn[3];
    kn4.x = kn4.x * cs[0] + sgn * kno.x * sn[0];
    kn4.y = kn4.y * cs[1] + sgn * kno.y * sn[1];
    kn4.z = kn4.z * cs[2] + sgn * kno.z * sn[2];
    kn4.w = kn4.w * cs[3] + sgn * kno.w * sn[3];
    // fold 1/sqrt(HD) into q
    q4.x *= SCALE; q4.y *= SCALE; q4.z *= SCALE; q4.w *= SCALE;

    float l_run = 0.f;
    float4 o_acc = make_float4(0.f, 0.f, 0.f, 0.f);

    int s0 = start + w * 2;           // wave-uniform base
    int sl_ = s0 + half;              // this lane's position

    float4 k4 = make_float4(0,0,0,0), v4 = make_float4(0,0,0,0);
    if (s0 < end) {
        int blk = bofs[b * MAXBLK + (sl_ >> 6)];
        size_t base = ((size_t)(blk * BLKSZ + (sl_ & 63)) * NHEAD + h) * HDIM + dbase;
        k4 = *(const float4*)(k_cache + base);
        v4 = *(const float4*)(v_cache + base);
        if (sl_ == pos) { k4 = kn4; v4 = vn4; }
    }
    while (s0 < end) {
        int sn0 = s0 + 8;
        int sln = sl_ + 8;
        float4 k4n = make_float4(0,0,0,0), v4n = make_float4(0,0,0,0);
        if (sn0 < end) {
            int blk = bofs[b * MAXBLK + (sln >> 6)];
            size_t base = ((size_t)(blk * BLKSZ + (sln & 63)) * NHEAD + h) * HDIM + dbase;
            k4n = *(const float4*)(k_cache + base);
            v4n = *(const float4*)(v_cache + base);
            if (sln == pos) { k4n = kn4; v4n = vn4; }
        }
        float d = q4.x * k4.x + q4.y * k4.y + q4.z * k4.z + q4.w * k4.w;
        d += __shfl_xor(d, 1); d += __shfl_xor(d, 2); d += __shfl_xor(d, 4);
        d += __shfl_xor(d, 8); d += __shfl_xor(d, 16);
        float p = (sl_ <= pos) ? __expf(d) : 0.f;
        l_run += p;
        o_acc.x += p * v4.x; o_acc.y += p * v4.y;
        o_acc.z += p * v4.z; o_acc.w += p * v4.w;
        k4 = k4n; v4 = v4n; s0 = sn0; sl_ = sln;
    }

    // combine halves (same dims, different positions)
    l_run  += __shfl_xor(l_run, 32);
    o_acc.x += __shfl_xor(o_acc.x, 32);
    o_acc.y += __shfl_xor(o_acc.y, 32);
    o_acc.z += __shfl_xor(o_acc.z, 32);
    o_acc.w += __shfl_xor(o_acc.w, 32);

    __shared__ float sacc[4][HDIM];
    __shared__ float slr[4];
    if (half == 0) *(float4*)&sacc[w][dbase] = o_acc;
    if (lane == 0) slr[w] = l_run;
    __syncthreads();

    float* part = partials + (size_t)(bh * NSPLIT + split) * PSTRIDE;
    if (tid < HDIM)
        part[4 + tid] = sacc[0][tid] + sacc[1][tid] + sacc[2][tid] + sacc[3][tid];
    if (tid == 0)
        part[0] = slr[0] + slr[1] + slr[2] + slr[3];
}

// ---------------- Combine splits (no per-split max; shared implicit max=0). grid 128 x 128.
__global__ void combine_kernel(const float* __restrict__ partials, float* __restrict__ o)
{
    int bh = blockIdx.x;
    int i = threadIdx.x;    // 0..127
    int b = bh >> 4, h = bh & 15;
    const float* base = partials + (size_t)bh * NSPLIT * PSTRIDE;
    float L = 0.f, a = 0.f;
    #pragma unroll
    for (int sp = 0; sp < NSPLIT; ++sp) {
        L += base[sp * PSTRIDE];
        a += base[sp * PSTRIDE + 4 + i];
    }
    o[b * DMODEL + h * HDIM + i] = a / L;
}

// ---------------- Output projection. grid 256 x 256. Wave = 2 columns.
__global__ __launch_bounds__(256) void oproj_kernel(
    const float* __restrict__ o,
    const float* __restrict__ Wo, const float* __restrict__ bo,
    float* __restrict__ out)
{
    __shared__ float ol[BATCH * DMODEL];   // 64 KB
    {
        const float4* o4 = (const float4*)o;
        float4* ol4 = (float4*)ol;
        for (int idx = threadIdx.x; idx < BATCH * DMODEL / 4; idx += 256)
            ol4[idx] = o4[idx];
    }
    __syncthreads();

    int wave = threadIdx.x >> 6;
    int lane = threadIdx.x & 63;
    int gw = blockIdx.x * 4 + wave;     // 0..1023
    int col0 = gw * 2;                  // 0..2046

    float acc[2][BATCH];
    #pragma unroll
    for (int c = 0; c < 2; ++c)
        #pragma unroll
        for (int b = 0; b < BATCH; ++b) acc[c][b] = 0.f;

    #pragma unroll
    for (int it = 0; it < DMODEL / 256; ++it) {
        int k0 = it * 256 + lane * 4;
        float4 w[2];
        #pragma unroll
        for (int c = 0; c < 2; ++c)
            w[c] = *(const float4*)(Wo + (size_t)(col0 + c) * DMODEL + k0);
        #pragma unroll
        for (int b = 0; b < BATCH; ++b) {
            float4 hv = *(const float4*)(ol + b * DMODEL + k0);
            #pragma unroll
            for (int c = 0; c < 2; ++c)
                acc[c][b] += hv.x * w[c].x + hv.y * w[c].y + hv.z * w[c].z + hv.w * w[c].w;
        }
    }

    #pragma unroll
    for (int c = 0; c < 2; ++c) {
        #pragma unroll
        for (int b = 0; b < BATCH; ++b) {
            float r = acc[c][b];
            r += __shfl_xor(r, 32); r += __shfl_xor(r, 16); r += __shfl_xor(r, 8);
            r += __shfl_xor(r, 4);  r += __shfl_xor(r, 2);  r += __shfl_xor(r, 1);
            if (lane == 0)
                out[b * DMODEL + col0 + c] = r + bo[col0 + c];
        }
    }
}

extern "C" void kernel_launch(void* const* d_in, const int* in_sizes, int n_in,
                              void* d_out, int out_size, void* d_ws, size_t ws_size,
                              hipStream_t stream) {
    const float* hs      = (const float*)d_in[0];
    const float* k_cache = (const float*)d_in[1];
    const float* v_cache = (const float*)d_in[2];
    const float* Wq      = (const float*)d_in[3];
    const float* bq      = (const float*)d_in[4];
    const float* Wk      = (const float*)d_in[5];
    const float* bk      = (const float*)d_in[6];
    const float* Wv      = (const float*)d_in[7];
    const float* bv      = (const float*)d_in[8];
    const float* Wo      = (const float*)d_in[9];
    const float* bo      = (const float*)d_in[10];
    const int*   hist    = (const int*)d_in[11];
    const int*   bofs    = (const int*)d_in[12];
    float* out = (float*)d_out;

    float* ws = (float*)d_ws;
    float* qkv      = ws;                                   // 3*8*2048 = 49152 floats
    float* partials = ws + 49152;                           // 128*16*132 = 270336 floats
    float* o        = ws + 49152 + 270336;                  // 16384 floats

    qkv_kernel<<<512, 256, 0, stream>>>(hs, Wq, bq, Wk, bk, Wv, bv, qkv);
    attn_kernel<<<dim3(NSPLIT, BATCH * NHEAD), 256, 0, stream>>>(qkv, k_cache, v_cache, hist, bofs, partials);
    combine_kernel<<<BATCH * NHEAD, HDIM, 0, stream>>>(partials, o);
    oproj_kernel<<<256, 256, 0, stream>>>(o, Wo, bo, out);
}